// Round 5
// baseline (68.069 us; speedup 1.0000x reference)
//
#include <hip/hip_runtime.h>
#include <math.h>

#define EPS 1e-6f

// Input: feat_map [T=32][D=256][H=56][W=56] fp32.
// Flat float4 view: 6,422,528 float4; per t: 200704 float4; per d-slice: 784 float4.
//
// loc_reduce: copy-ubench geometry. 1568 blocks x 256 threads (32 t x 49 pos-blocks,
//   ~6 blocks/CU). Thread owns r = pb*256+tid in [0,12544); since 12544 = 16*784 its
//   in-slice position pos = r%784 (-> h=pos/14, w-group v=pos%14) is FIXED across the
//   16 iterations j = t*200704 + r + 12544*i. One float4 load + 8 VALU per iteration;
//   latency hidden by TLP (~25 waves/CU), chip-wide access = 32 contiguous sweeping
//   fronts. Epilogue: LDS histogram -> disjoint 224-float partial per block.
//
// ws partials: [block=(t*49+pb)][arr][56], arr: 0=s1h,1=s2h,2=s1w,3=s2w (351,232 floats)
// out layout: [0]=tot, then log10(ga1)[32*56], ga2, ga3, ga4.

__global__ __launch_bounds__(256) void loc_reduce(const float* __restrict__ f,
                                                  float* __restrict__ ws) {
    const int b   = blockIdx.x;          // 0..1567
    const int t   = b / 49;
    const int pb  = b % 49;
    const int tid = threadIdx.x;
    const int r   = pb * 256 + tid;      // 0..12543 within t
    const int pos = r % 784;             // fixed in-slice float4 position
    const int h   = pos / 14;
    const int v   = pos % 14;            // w = 4v..4v+3

    const float4* p = reinterpret_cast<const float4*>(f) + (size_t)t * 200704 + r;

    float s10 = 0.f, s11 = 0.f, s12 = 0.f, s13 = 0.f;
    float s20 = 0.f, s21 = 0.f, s22 = 0.f, s23 = 0.f;

    for (int i = 0; i < 16; ++i) {
        float4 x = p[(size_t)i * 12544];
        s10 += x.x; s11 += x.y; s12 += x.z; s13 += x.w;
        s20 += x.x * x.x; s21 += x.y * x.y; s22 += x.z * x.z; s23 += x.w * x.w;
    }

    __shared__ float ls[224];
    if (tid < 224) ls[tid] = 0.f;
    __syncthreads();

    atomicAdd(&ls[0 * 56 + h], s10 + s11 + s12 + s13);
    atomicAdd(&ls[1 * 56 + h], s20 + s21 + s22 + s23);
    atomicAdd(&ls[112 + 4 * v + 0], s10);
    atomicAdd(&ls[112 + 4 * v + 1], s11);
    atomicAdd(&ls[112 + 4 * v + 2], s12);
    atomicAdd(&ls[112 + 4 * v + 3], s13);
    atomicAdd(&ls[168 + 4 * v + 0], s20);
    atomicAdd(&ls[168 + 4 * v + 1], s21);
    atomicAdd(&ls[168 + 4 * v + 2], s22);
    atomicAdd(&ls[168 + 4 * v + 3], s23);
    __syncthreads();

    if (tid < 224) ws[(size_t)b * 224 + tid] = ls[tid];
}

__global__ __launch_bounds__(1024) void loc_finalize(const float* __restrict__ ws,
                                                     float* __restrict__ out) {
    __shared__ float sums[7168];  // [t][arr][56] = 28 KB
    const int tid = threadIdx.x;

    // Phase 1: fold the 49 pos-block partials per t (coalesced; 7 outputs/thread).
    #pragma unroll
    for (int k = 0; k < 7; ++k) {
        const int o  = tid + 1024 * k;   // o = t*224 + idx
        const int t  = o / 224;
        const int k2 = o % 224;
        float a = 0.f;
        for (int pb = 0; pb < 49; ++pb)
            a += ws[(size_t)(t * 49 + pb) * 224 + k2];
        sums[o] = a;
    }
    __syncthreads();

    // Phase 2: 64 threads = (t 0..31) x (H-axis / W-axis); serial 56-elem scans.
    if (tid < 64) {
        const int t    = tid & 31;
        const bool isW = tid >= 32;

        const float* s1 = &sums[t * 224 + (isW ? 112 : 0)];
        const float* s2 = &sums[t * 224 + (isW ? 168 : 56)];
        float* osuf = out + 1 + (isW ? 3584 : 0)    + t * 56;  // ga1 / ga3
        float* opre = out + 1 + (isW ? 5376 : 1792) + t * 56;  // ga2 / ga4

        const float n_per = 14336.f;  // D*W == D*H
        float part = 0.f;

        float a1 = 0.f, a2 = 0.f;
        for (int i = 55; i >= 0; --i) {            // suffix
            a1 += s1[i]; a2 += s2[i];
            const float n  = n_per * (float)(56 - i);
            const float ga = sqrtf(a2 + 2.0f * EPS * a1 + (EPS * EPS) * n);
            osuf[i] = log10f(ga);
            part += ga + EPS;
        }
        a1 = 0.f; a2 = 0.f;
        for (int i = 0; i < 56; ++i) {             // prefix
            a1 += s1[i]; a2 += s2[i];
            const float n  = n_per * (float)(i + 1);
            const float ga = sqrtf(a2 + 2.0f * EPS * a1 + (EPS * EPS) * n);
            opre[i] = log10f(ga);
            part += ga + EPS;
        }

        #pragma unroll
        for (int off = 32; off; off >>= 1) part += __shfl_down(part, off);
        if (tid == 0) out[0] = part * (1.0f / 128.0f);  // /T /4
    }
}

extern "C" void kernel_launch(void* const* d_in, const int* in_sizes, int n_in,
                              void* d_out, int out_size, void* d_ws, size_t ws_size,
                              hipStream_t stream) {
    const float* f = (const float*)d_in[0];
    float* out = (float*)d_out;
    float* ws  = (float*)d_ws;

    loc_reduce<<<dim3(1568), dim3(256), 0, stream>>>(f, ws);
    loc_finalize<<<dim3(1), dim3(1024), 0, stream>>>(ws, out);
}